// Round 8
// baseline (235.728 us; speedup 1.0000x reference)
//
#include <hip/hip_runtime.h>
#include <float.h>
#include <stdint.h>

#pragma clang fp contract(off)

#define BATCH   2
#define N_ANCH  49104
#define NCLS    20
#define MAXDET  300
#define CAP     1024               /* pow2; expected candidates/class ~818 +- 28 */
#define KMAT    512                /* LDS bit-matrix rows (greedy prefix) */
#define MATW    8                  /* KMAT/64 words per row */
#define NMS_T   512
#define FB_PER  96                 /* ceil(N_ANCH/512) */
#define TSEL    0.59f
#define SCTHR   0.05f
#define NEGF    (-1e9f)
#define HIC     511.0f
#define STDF    0.2f
#define DEAD    (-FLT_MAX)
#define BXL(j)  ((j) + ((j) >> 4))   /* bank-spread padding for bxl */

typedef unsigned long long u64;

// ---- workspace layout (bytes) ----
static constexpr size_t OFF_BOXES = 0;                                    // [B][N][4] f32
static constexpr size_t SZ_BOXES  = (size_t)BATCH * N_ANCH * 4 * 4;
static constexpr size_t OFF_CS    = OFF_BOXES + SZ_BOXES;                 // [B*C][CAP] f32
static constexpr size_t SZ_CS     = (size_t)BATCH * NCLS * CAP * 4;
static constexpr size_t OFF_CI    = OFF_CS + SZ_CS;                       // [B*C][CAP] i32
static constexpr size_t SZ_CI     = SZ_CS;
static constexpr size_t OFF_CNT   = OFF_CI + SZ_CI;                       // [B*C] i32
static constexpr size_t SZ_CNT    = (size_t)BATCH * NCLS * 4;
static constexpr size_t OFF_SS    = OFF_CNT + ((SZ_CNT + 15) & ~(size_t)15); // [B*C][300] f32
static constexpr size_t SZ_SS    = (size_t)BATCH * NCLS * MAXDET * 4;
static constexpr size_t OFF_SI    = OFF_SS + SZ_SS;                       // [B*C][300] i32

// Exact replica of reference IoU decision (fallback path):
// iou = inter / (((a_b + area) - inter) + 1e-8); suppress iff iou > 0.5
__device__ __forceinline__ bool iou_gt(float b0, float b1, float b2, float b3,
                                       float ab, float4 e) {
#pragma clang fp contract(off)
  float xx1 = fmaxf(b0, e.x);
  float yy1 = fmaxf(b1, e.y);
  float xx2 = fminf(b2, e.z);
  float yy2 = fminf(b3, e.w);
  float iw = fmaxf(xx2 - xx1, 0.0f);
  float ih = fmaxf(yy2 - yy1, 0.0f);
  float inter = iw * ih;
  float area = (e.z - e.x) * (e.w - e.y);
  float den = ab + area;
  den = den - inter;
  den = den + 1e-8f;
  float iou = inter / den;          // IEEE f32 divide
  return iou > 0.5f;
}

// Bit-exact fast IoU decision (no divide):
// fl(inter/den) > 0.5  <=>  inter/den > 0.5 + 2^-25  (tie rounds to even 0.5)
// (double)inter and (double)den exact; den*(0.5+2^-25) is a 24x25-bit
// product = 49 bits < 53 -> exact comparison. Decision-identical to iou_gt.
__device__ __forceinline__ bool iou_gt_fast(float b0, float b1, float b2, float b3,
                                            float ab, float4 e, float earea) {
#pragma clang fp contract(off)
  float xx1 = fmaxf(b0, e.x);
  float yy1 = fmaxf(b1, e.y);
  float xx2 = fminf(b2, e.z);
  float yy2 = fminf(b3, e.w);
  float iw = fmaxf(xx2 - xx1, 0.0f);
  float ih = fmaxf(yy2 - yy1, 0.0f);
  float inter = iw * ih;
  float den = ab + earea;
  den = den - inter;
  den = den + 1e-8f;
  return (double)inter > (double)den * 0x1.000001p-1;   // 0.5 + 2^-25
}

// block argmax (score desc, index asc); broadcast via LDS (full-N fallback)
__device__ __forceinline__ void block_argmax(float bs, int bn,
                                             float* red_s, int* red_n,
                                             float* g_s, int* g_n) {
  for (int off = 32; off > 0; off >>= 1) {
    float os = __shfl_down(bs, off);
    int   on = __shfl_down(bn, off);
    if (os > bs || (os == bs && on < bn)) { bs = os; bn = on; }
  }
  int tid = threadIdx.x;
  if ((tid & 63) == 0) { red_s[tid >> 6] = bs; red_n[tid >> 6] = bn; }
  __syncthreads();
  if (tid == 0) {
    float gs = red_s[0]; int gn = red_n[0];
    for (int wv = 1; wv < NMS_T / 64; ++wv) {
      float rs = red_s[wv]; int rn = red_n[wv];
      if (rs > gs || (rs == gs && rn < gn)) { gs = rs; gn = rn; }
    }
    *g_s = gs; *g_n = gn;
  }
  __syncthreads();
}

// K1: decode+clip boxes, gather per-(b,c) candidates with score > TSEL.
__global__ __launch_bounds__(256) void dec_gather(
    const float* __restrict__ anchors, const float* __restrict__ deltas,
    const float* __restrict__ cls, float* __restrict__ boxes,
    float* __restrict__ cand_s, int* __restrict__ cand_i,
    int* __restrict__ cnt) {
#pragma clang fp contract(off)
  __shared__ int lcnt[BATCH * NCLS];
  __shared__ int lbase[BATCH * NCLS];
  const int tid = threadIdx.x;
  const int id = blockIdx.x * 256 + tid;       // id = b*N + n
  const bool live = id < BATCH * N_ANCH;

  int b = 0, n = 0;
  float r[NCLS];
  if (live) {
    b = id / N_ANCH;
    n = id - b * N_ANCH;
    float4 a = ((const float4*)anchors)[id];
    float4 d = ((const float4*)deltas)[id];
    float w = a.z - a.x;
    float h = a.w - a.y;
    float t;
    t = d.x * STDF; float x1 = a.x + t * w;    // (d*0.2f)*w then add — matches np
    t = d.y * STDF; float y1 = a.y + t * h;
    t = d.z * STDF; float x2 = a.z + t * w;
    t = d.w * STDF; float y2 = a.w + t * h;
    float4 bx;
    bx.x = fminf(fmaxf(x1, 0.0f), HIC);
    bx.y = fminf(fmaxf(y1, 0.0f), HIC);
    bx.z = fminf(fmaxf(x2, 0.0f), HIC);
    bx.w = fminf(fmaxf(y2, 0.0f), HIC);
    ((float4*)boxes)[id] = bx;
    const float4* rv = (const float4*)(cls + (size_t)id * NCLS);
#pragma unroll
    for (int k = 0; k < NCLS / 4; ++k) {
      float4 v = rv[k];
      r[k * 4 + 0] = v.x; r[k * 4 + 1] = v.y;
      r[k * 4 + 2] = v.z; r[k * 4 + 3] = v.w;
    }
  }

  if (tid < BATCH * NCLS) lcnt[tid] = 0;
  __syncthreads();

  if (live) {
#pragma unroll
    for (int c = 0; c < NCLS; ++c) {
      if (r[c] > TSEL) atomicAdd(&lcnt[b * NCLS + c], 1);
    }
  }
  __syncthreads();

  if (tid < BATCH * NCLS) {
    int v = lcnt[tid];
    if (v > 0) lbase[tid] = atomicAdd(cnt + tid, v);
    lcnt[tid] = 0;                              // reuse as phase-C cursor
  }
  __syncthreads();

  if (live) {
#pragma unroll
    for (int c = 0; c < NCLS; ++c) {
      float s = r[c];
      if (s > TSEL) {
        int bc = b * NCLS + c;
        int p = atomicAdd(&lcnt[bc], 1);
        int pos = lbase[bc] + p;
        if (pos < CAP) {
          cand_s[(size_t)bc * CAP + pos] = s;
          cand_i[(size_t)bc * CAP + pos] = n;
        }
      }
    }
  }
}

// K2: per-(b,c) NMS. Sort <=1024 candidates desc; 512x512 LDS bit-matrix over
// the top-512; single-lane monotone bit-walk (greedy prefix is final); then
// BLOCK-PARALLEL tail filter vs the prefix accepts + wave mini-scan among the
// surviving tail candidates. Exact full-N fallback if overflow / <300 accepts.
__global__ __launch_bounds__(NMS_T) void nms_kernel(
    const float* __restrict__ cls, const float* __restrict__ boxes,
    const float* __restrict__ cand_s, const int* __restrict__ cand_i,
    const int* __restrict__ cnt,
    float* __restrict__ sel_s, int* __restrict__ sel_i) {
#pragma clang fp contract(off)
  __shared__ u64    keys[CAP];                 // 8 KB
  __shared__ u64    mat[KMAT * MATW];          // 32 KB; reused as accb/acca
  __shared__ float4 bxl[CAP + CAP / 16];       // 17 KB (padded: BXL)
  __shared__ int    apos[MAXDET];              // accepted sorted-positions
  __shared__ u64    tailmask[8];               // tail survivors of prefix filter
  __shared__ int    A_sh;
  __shared__ float  red_s[NMS_T / 64];
  __shared__ int    red_n[NMS_T / 64];
  __shared__ float  g_s;
  __shared__ int    g_n;

  const int bc  = blockIdx.x;
  const int b   = bc / NCLS;
  const int c   = bc - b * NCLS;
  const int tid = threadIdx.x;
  const int count = cnt[bc];
  float* ss = sel_s + (size_t)bc * MAXDET;
  int*   si = sel_i + (size_t)bc * MAXDET;
  const float4* bxs = (const float4*)boxes + (size_t)b * N_ANCH;
  bool fullfb = (count > CAP);      // overflow -> subset invalid -> full-N

  if (!fullfb) {
    const float* cs = cand_s + (size_t)bc * CAP;
    const int*   ci = cand_i + (size_t)bc * CAP;
    // keys: (score_bits|msb)<<32 | ~idx — descending == greedy argmax order
    for (int g = tid; g < CAP; g += NMS_T) {
      u64 k = 0ull;                              // padding sinks to end
      if (g < count) {
        unsigned int u = __float_as_uint(cs[g]) | 0x80000000u;  // scores > 0
        k = ((u64)u << 32) | (unsigned int)(~ci[g]);
      }
      keys[g] = k;
    }
    __syncthreads();
    // bitonic sort (descending), 1024 keys, 512 threads
    for (int kk = 2; kk <= CAP; kk <<= 1) {
      for (int j = kk >> 1; j > 0; j >>= 1) {
#pragma unroll
        for (int p = 0; p < CAP / NMS_T; ++p) {
          int i = tid + p * NMS_T;
          int ixj = i ^ j;
          if (ixj > i) {
            u64 a = keys[i], bk = keys[ixj];
            bool ddir = ((i & kk) == 0);
            if ((a < bk) == ddir) { keys[i] = bk; keys[ixj] = a; }
          }
        }
        __syncthreads();
      }
    }
    // stage ALL sorted candidate boxes
    for (int g = tid; g < count; g += NMS_T) {
      int idx = (int)(~((unsigned int)keys[g]));
      bxl[BXL(g)] = bxs[idx];
    }
    __syncthreads();
    const int KM = (count < KMAT) ? count : KMAT;
    // build 512x512 IoU bit-matrix. w = t>>7 wave-uniform -> e reads broadcast.
    // Unwritten / sub-diagonal words hold garbage — harmless (any bit j < row
    // is already decided when the walk accepts that row).
    for (int t = tid; t < (KMAT / 4) * MATW; t += NMS_T) {
      const int w  = t >> 7;                    // uniform within a wave
      const int rq = t & 127;
      const int i0 = rq * 4;
      const int jbase = w * 64;
      if (i0 < KM && jbase < KM && jbase + 64 > i0) {
        const int iA = i0, iB = min(i0 + 1, KM - 1),
                  iC = min(i0 + 2, KM - 1), iD = min(i0 + 3, KM - 1);
        float4 rA = bxl[BXL(iA)], rB = bxl[BXL(iB)],
               rC = bxl[BXL(iC)], rD = bxl[BXL(iD)];
        float aA = (rA.z - rA.x) * (rA.w - rA.y);
        float aB = (rB.z - rB.x) * (rB.w - rB.y);
        float aC = (rC.z - rC.x) * (rC.w - rC.y);
        float aD = (rD.z - rD.x) * (rD.w - rD.y);
        const int jmax = min(64, KM - jbase);
        u64 w0 = 0, w1 = 0, w2 = 0, w3 = 0;
        for (int jj = 0; jj < jmax; ++jj) {
          float4 e = bxl[BXL(jbase + jj)];      // broadcast (uniform address)
          float ea = (e.z - e.x) * (e.w - e.y);
          w0 |= (u64)iou_gt_fast(rA.x, rA.y, rA.z, rA.w, aA, e, ea) << jj;
          w1 |= (u64)iou_gt_fast(rB.x, rB.y, rB.z, rB.w, aB, e, ea) << jj;
          w2 |= (u64)iou_gt_fast(rC.x, rC.y, rC.z, rC.w, aC, e, ea) << jj;
          w3 |= (u64)iou_gt_fast(rD.x, rD.y, rD.z, rD.w, aD, e, ea) << jj;
        }
        mat[(i0 + 0) * MATW + w] = w0;
        mat[(i0 + 1) * MATW + w] = w1;
        mat[(i0 + 2) * MATW + w] = w2;
        mat[(i0 + 3) * MATW + w] = w3;
      }
    }
    __syncthreads();
    // single-lane monotone-cursor bit-walk over the greedy prefix
    if (tid == 0) {
      u64 m[MATW];
#pragma unroll
      for (int w = 0; w < MATW; ++w) {
        int base = w * 64;
        m[w] = (base >= KM) ? ~0ull
             : ((KM - base >= 64) ? 0ull : (~0ull << (KM - base)));
      }
      int A = 0, w0 = 0;
      while (true) {
        while (w0 < MATW && m[w0] == ~0ull) ++w0;
        if (w0 == MATW) break;
        const int pos = (w0 << 6) + __builtin_ctzll(~m[w0]);
        apos[A] = pos;
        A++;
        if (A == MAXDET) break;
        m[w0] |= 1ull << (pos & 63);             // self bit
        const u64* rw = &mat[pos * MATW];
#pragma unroll
        for (int w = 0; w < MATW; ++w) m[w] |= rw[w];
      }
      A_sh = A;
    }
    __syncthreads();
    const int A0 = A_sh;

    // ---- block-parallel tail: prefix decisions (0..KMAT) are final, so
    // (1) filter every tail candidate vs the A0 prefix accepts in parallel,
    // (2) wave mini-scan resolves survivors among themselves.
    if (A0 < MAXDET && count > KMAT) {
      float4* accb = (float4*)mat;               // mat no longer needed
      float*  acca = (float*)(accb + MAXDET);
      if (tid < A0) {
        float4 v = bxl[BXL(apos[tid])];
        accb[tid] = v;
        acca[tid] = (v.z - v.x) * (v.w - v.y);
      }
      __syncthreads();
      // (1) parallel prefix-filter: thread tid owns tail candidate g
      {
        const int g = KMAT + tid;
        bool alive = (g < count);
        float4 bx = {0.0f, 0.0f, 0.0f, 0.0f};
        float carea = 0.0f;
        if (alive) {
          bx = bxl[BXL(g)];
          carea = (bx.z - bx.x) * (bx.w - bx.y);
        }
        for (int a = 0; a < A0; ++a) {           // accb reads broadcast
          if (!alive) break;
          float4 abx = accb[a];
          float  aar = acca[a];
          if (iou_gt_fast(abx.x, abx.y, abx.z, abx.w, aar, bx, carea))
            alive = false;
        }
        u64 bal = __ballot(alive);
        if ((tid & 63) == 0) tailmask[tid >> 6] = bal;
      }
      __syncthreads();
      // (2) single-wave mini-scan over surviving tail candidates; phase-1
      // tests only vs tail accepts (appended at accb[A0..])
      if (tid < 64) {
        const int lane = tid;
        int A = A0;
        bool done = false;
        for (int w = 0; w < 8 && !done; ++w) {
          u64 mask = tailmask[w];
          if (!mask) continue;
          const int g = KMAT + (w << 6) + lane;
          const bool mine0 = (mask >> lane) & 1;
          float4 bx = {0.0f, 0.0f, 0.0f, 0.0f};
          float carea = 0.0f;
          if (mine0) {
            bx = bxl[BXL(g)];
            carea = (bx.z - bx.x) * (bx.w - bx.y);
          }
          // phase 1: vs tail accepts from earlier words only
          bool alive = mine0;
          for (int a = A0; a < A; ++a) {
            if (!alive) break;
            float4 abx = accb[a];
            float  aar = acca[a];
            if (iou_gt_fast(abx.x, abx.y, abx.z, abx.w, aar, bx, carea))
              alive = false;
          }
          u64 pend = __ballot(alive);
          while (pend) {
            const int jj = __ffsll((long long)pend) - 1;
            pend &= pend - 1;
            const float jx = __shfl(bx.x, jj);
            const float jy = __shfl(bx.y, jj);
            const float jz = __shfl(bx.z, jj);
            const float jw = __shfl(bx.w, jj);
            if (lane == jj) {
              apos[A] = g;
              accb[A] = bx; acca[A] = carea;
            }
            A++;
            if (A == MAXDET) { done = true; break; }
            if (pend) {
              const float jar = (jz - jx) * (jw - jy);
              bool mine = (pend >> lane) & 1;
              bool sup = mine &&
                  iou_gt_fast(jx, jy, jz, jw, jar, bx, carea);
              pend &= ~__ballot(sup);
            }
          }
        }
        if (lane == 0) A_sh = A;
      }
      __syncthreads();
    }

    if (A_sh >= MAXDET) {
      if (tid < MAXDET) {                        // parallel emit
        int p = apos[tid];
        u64 key = keys[p];
        ss[tid] = __uint_as_float(((unsigned int)(key >> 32)) & 0x7FFFFFFFu);
        si[tid] = (int)(~((unsigned int)key));
      }
      return;
    }
    fullfb = true;    // genuinely <300 survivors -> replicate reference fully
  }

  // ---- exact full-N fallback (correctness insurance)
  {
    const float* crow = cls + ((size_t)b * N_ANCH) * NCLS + c;  // stride NCLS
    const int base = tid * FB_PER;   // contiguous ownership; 512*96 >= N
    float sc[FB_PER];
#pragma unroll
    for (int m = 0; m < FB_PER; ++m) {
      int n = base + m;
      float v = DEAD;
      if (n < N_ANCH) {
        float r = crow[(size_t)n * NCLS];
        v = (r > SCTHR) ? r : NEGF;
      }
      sc[m] = v;
    }
    __syncthreads();
    for (int k = 0; k < MAXDET; ++k) {
      float bs = DEAD; int bn = 0x7FFFFFFF;
#pragma unroll
      for (int m = 0; m < FB_PER; ++m) {
        if (sc[m] > bs) { bs = sc[m]; bn = base + m; }
      }
      block_argmax(bs, bn, red_s, red_n, &g_s, &g_n);
      const float gs = g_s; const int gn = g_n;
      if (tid == 0) { ss[k] = gs; si[k] = gn; }
      float4 w4 = bxs[gn];
      float ab = (w4.z - w4.x) * (w4.w - w4.y);
#pragma unroll
      for (int m = 0; m < FB_PER; ++m) {
        if (sc[m] > NEGF) {
          float4 e = bxs[base + m];
          if (iou_gt(w4.x, w4.y, w4.z, w4.w, ab, e)) sc[m] = NEGF;
        }
      }
    }
  }
}

// K3: stable global top-300 per batch. Pivot prune (P = min_c key[c][29]
// guarantees >=600 keys >= P >= all top-300), then exact rank-count on ~600.
__global__ __launch_bounds__(512) void topk_kernel(
    const float* __restrict__ sel_s, const int* __restrict__ sel_i,
    const float* __restrict__ boxes, float* __restrict__ out) {
#pragma clang fp contract(off)
  __shared__ u64 keys[NCLS * MAXDET];   // 48 KB
  __shared__ int ccnt[NCLS];
  __shared__ u64 Psh;
  const int b = blockIdx.x;
  const int tid = threadIdx.x;
  const float* ssb = sel_s + (size_t)b * NCLS * MAXDET;
  const int*   sib = sel_i + (size_t)b * NCLS * MAXDET;
  for (int e = tid; e < NCLS * MAXDET; e += 512) {
    unsigned int u = __float_as_uint(ssb[e]);
    u = (u & 0x80000000u) ? ~u : (u | 0x80000000u);    // order-preserving map
    keys[e] = ((u64)u << 32) | (u64)(0xFFFFFFFFu - (unsigned)e);
  }
  __syncthreads();
  if (tid == 0) {
    u64 mn = ~0ull;
    for (int c = 0; c < NCLS; ++c) {
      u64 v = keys[c * MAXDET + 29];
      if (v < mn) mn = v;
    }
    Psh = mn;
  }
  __syncthreads();
  const u64 P = Psh;
  if (tid < NCLS) {                      // per-class count of keys >= P
    const u64* kc = keys + tid * MAXDET;
    int lo = 0, hi = MAXDET;
    while (lo < hi) { int mid = (lo + hi) >> 1; if (kc[mid] >= P) lo = mid + 1; else hi = mid; }
    ccnt[tid] = lo;
  }
  __syncthreads();
  for (int e = tid; e < NCLS * MAXDET; e += 512) {
    int c = e / MAXDET;
    int j = e - c * MAXDET;
    if (j >= ccnt[c]) continue;          // key < P -> rank >= 600 -> excluded
    u64 ke = keys[e];
    int rank = 0;
    for (int c2 = 0; c2 < NCLS; ++c2) {
      const u64* kc = keys + c2 * MAXDET;
      int lo = 0, hi = ccnt[c2];         // keys beyond ccnt are < P <= ke
      while (lo < hi) {
        int mid = (lo + hi) >> 1;
        if (kc[mid] > ke) lo = mid + 1; else hi = mid;
      }
      rank += lo;
    }
    if (rank < MAXDET) {
      float s = ssb[e];
      int   n = sib[e];
      int   cc = c;
      bool valid = (s > NEGF * 0.5f);
      float4 bx = ((const float4*)boxes)[(size_t)b * N_ANCH + n];
      float* ob = out + ((size_t)b * MAXDET + rank) * 4;
      ob[0] = valid ? bx.x : -1.0f;
      ob[1] = valid ? bx.y : -1.0f;
      ob[2] = valid ? bx.z : -1.0f;
      ob[3] = valid ? bx.w : -1.0f;
      out[(size_t)BATCH * MAXDET * 4 + (size_t)b * MAXDET + rank] = valid ? s : -1.0f;
      out[(size_t)BATCH * MAXDET * 5 + (size_t)b * MAXDET + rank] =
          valid ? (float)cc : -1.0f;
    }
  }
}

extern "C" void kernel_launch(void* const* d_in, const int* in_sizes, int n_in,
                              void* d_out, int out_size, void* d_ws, size_t ws_size,
                              hipStream_t stream) {
  (void)in_sizes; (void)n_in; (void)out_size; (void)ws_size;
  const float* anchors = (const float*)d_in[1];
  const float* deltas  = (const float*)d_in[2];
  const float* cls     = (const float*)d_in[3];   // d_in[0] = image: only shape used
  char* ws = (char*)d_ws;
  float* boxes  = (float*)(ws + OFF_BOXES);
  float* cand_s = (float*)(ws + OFF_CS);
  int*   cand_i = (int*)  (ws + OFF_CI);
  int*   cnt    = (int*)  (ws + OFF_CNT);
  float* sel_s  = (float*)(ws + OFF_SS);
  int*   sel_i  = (int*)  (ws + OFF_SI);

  hipMemsetAsync(cnt, 0, SZ_CNT, stream);   // ws is re-poisoned 0xAA each call

  dec_gather<<<(BATCH * N_ANCH + 255) / 256, 256, 0, stream>>>(
      anchors, deltas, cls, boxes, cand_s, cand_i, cnt);
  nms_kernel<<<BATCH * NCLS, NMS_T, 0, stream>>>(
      cls, boxes, cand_s, cand_i, cnt, sel_s, sel_i);
  topk_kernel<<<BATCH, 512, 0, stream>>>(sel_s, sel_i, boxes, (float*)d_out);
}

// Round 9
// 227.151 us; speedup vs baseline: 1.0378x; 1.0378x over previous
//
#include <hip/hip_runtime.h>
#include <float.h>
#include <stdint.h>

#pragma clang fp contract(off)

#define BATCH   2
#define N_ANCH  49104
#define NCLS    20
#define MAXDET  300
#define CAP     1024               /* pow2; expected candidates/class ~818 +- 28 */
#define KMAT    512                /* bit-matrix rows (greedy prefix) */
#define MATW    8                  /* KMAT/64 words per row */
#define NMS_T   512
#define FB_PER  96                 /* ceil(N_ANCH/512) */
#define TSEL    0.59f
#define SCTHR   0.05f
#define NEGF    (-1e9f)
#define HIC     511.0f
#define STDF    0.2f
#define DEAD    (-FLT_MAX)
#define BXL(j)  ((j) + ((j) >> 4))   /* bank-spread padding for bxl */

typedef unsigned long long u64;

// ---- workspace layout (bytes) ----
static constexpr size_t OFF_BOXES = 0;                                    // [B][N][4] f32
static constexpr size_t SZ_BOXES  = (size_t)BATCH * N_ANCH * 4 * 4;
static constexpr size_t OFF_CS    = OFF_BOXES + SZ_BOXES;                 // [B*C][CAP] f32
static constexpr size_t SZ_CS     = (size_t)BATCH * NCLS * CAP * 4;
static constexpr size_t OFF_CI    = OFF_CS + SZ_CS;                       // [B*C][CAP] i32
static constexpr size_t SZ_CI     = SZ_CS;
static constexpr size_t OFF_CNT   = OFF_CI + SZ_CI;                       // [B*C] i32
static constexpr size_t SZ_CNT    = (size_t)BATCH * NCLS * 4;
static constexpr size_t OFF_SS    = OFF_CNT + ((SZ_CNT + 15) & ~(size_t)15); // [B*C][300] f32
static constexpr size_t SZ_SS    = (size_t)BATCH * NCLS * MAXDET * 4;
static constexpr size_t OFF_SI    = OFF_SS + SZ_SS;                       // [B*C][300] i32
static constexpr size_t SZ_SI    = SZ_SS;
static constexpr size_t OFF_SK   = (OFF_SI + SZ_SI + 127) & ~(size_t)127; // [B*C][CAP] u64 sorted keys
static constexpr size_t SZ_SK    = (size_t)BATCH * NCLS * CAP * 8;
static constexpr size_t OFF_SB   = OFF_SK + SZ_SK;                        // [B*C][CAP] float4 sorted boxes
static constexpr size_t SZ_SB    = (size_t)BATCH * NCLS * CAP * 16;
static constexpr size_t OFF_MAT  = OFF_SB + SZ_SB;                        // [B*C][MATW][KMAT] u64 (word-major)
static constexpr size_t SZ_MAT   = (size_t)BATCH * NCLS * KMAT * MATW * 8;

// Exact replica of reference IoU decision (full-N fallback):
// iou = inter / (((a_b + area) - inter) + 1e-8); suppress iff iou > 0.5
__device__ __forceinline__ bool iou_gt(float b0, float b1, float b2, float b3,
                                       float ab, float4 e) {
#pragma clang fp contract(off)
  float xx1 = fmaxf(b0, e.x);
  float yy1 = fmaxf(b1, e.y);
  float xx2 = fminf(b2, e.z);
  float yy2 = fminf(b3, e.w);
  float iw = fmaxf(xx2 - xx1, 0.0f);
  float ih = fmaxf(yy2 - yy1, 0.0f);
  float inter = iw * ih;
  float area = (e.z - e.x) * (e.w - e.y);
  float den = ab + area;
  den = den - inter;
  den = den + 1e-8f;
  float iou = inter / den;          // IEEE f32 divide
  return iou > 0.5f;
}

// Bit-exact fast IoU decision (no divide):
// fl(inter/den) > 0.5  <=>  inter/den > 0.5 + 2^-25  (tie rounds to even 0.5)
// (double)inter and (double)den exact; den*(0.5+2^-25) is a 24x25-bit
// product = 49 bits < 53 -> exact comparison. Decision-identical to iou_gt.
__device__ __forceinline__ bool iou_gt_fast(float b0, float b1, float b2, float b3,
                                            float ab, float4 e, float earea) {
#pragma clang fp contract(off)
  float xx1 = fmaxf(b0, e.x);
  float yy1 = fmaxf(b1, e.y);
  float xx2 = fminf(b2, e.z);
  float yy2 = fminf(b3, e.w);
  float iw = fmaxf(xx2 - xx1, 0.0f);
  float ih = fmaxf(yy2 - yy1, 0.0f);
  float inter = iw * ih;
  float den = ab + earea;
  den = den - inter;
  den = den + 1e-8f;
  return (double)inter > (double)den * 0x1.000001p-1;   // 0.5 + 2^-25
}

// block argmax (score desc, index asc); broadcast via LDS (full-N fallback)
__device__ __forceinline__ void block_argmax(float bs, int bn,
                                             float* red_s, int* red_n,
                                             float* g_s, int* g_n) {
  for (int off = 32; off > 0; off >>= 1) {
    float os = __shfl_down(bs, off);
    int   on = __shfl_down(bn, off);
    if (os > bs || (os == bs && on < bn)) { bs = os; bn = on; }
  }
  int tid = threadIdx.x;
  if ((tid & 63) == 0) { red_s[tid >> 6] = bs; red_n[tid >> 6] = bn; }
  __syncthreads();
  if (tid == 0) {
    float gs = red_s[0]; int gn = red_n[0];
    for (int wv = 1; wv < NMS_T / 64; ++wv) {
      float rs = red_s[wv]; int rn = red_n[wv];
      if (rs > gs || (rs == gs && rn < gn)) { gs = rs; gn = rn; }
    }
    *g_s = gs; *g_n = gn;
  }
  __syncthreads();
}

// K1: decode+clip boxes, gather per-(b,c) candidates with score > TSEL.
__global__ __launch_bounds__(256) void dec_gather(
    const float* __restrict__ anchors, const float* __restrict__ deltas,
    const float* __restrict__ cls, float* __restrict__ boxes,
    float* __restrict__ cand_s, int* __restrict__ cand_i,
    int* __restrict__ cnt) {
#pragma clang fp contract(off)
  __shared__ int lcnt[BATCH * NCLS];
  __shared__ int lbase[BATCH * NCLS];
  const int tid = threadIdx.x;
  const int id = blockIdx.x * 256 + tid;       // id = b*N + n
  const bool live = id < BATCH * N_ANCH;

  int b = 0, n = 0;
  float r[NCLS];
  if (live) {
    b = id / N_ANCH;
    n = id - b * N_ANCH;
    float4 a = ((const float4*)anchors)[id];
    float4 d = ((const float4*)deltas)[id];
    float w = a.z - a.x;
    float h = a.w - a.y;
    float t;
    t = d.x * STDF; float x1 = a.x + t * w;    // (d*0.2f)*w then add — matches np
    t = d.y * STDF; float y1 = a.y + t * h;
    t = d.z * STDF; float x2 = a.z + t * w;
    t = d.w * STDF; float y2 = a.w + t * h;
    float4 bx;
    bx.x = fminf(fmaxf(x1, 0.0f), HIC);
    bx.y = fminf(fmaxf(y1, 0.0f), HIC);
    bx.z = fminf(fmaxf(x2, 0.0f), HIC);
    bx.w = fminf(fmaxf(y2, 0.0f), HIC);
    ((float4*)boxes)[id] = bx;
    const float4* rv = (const float4*)(cls + (size_t)id * NCLS);
#pragma unroll
    for (int k = 0; k < NCLS / 4; ++k) {
      float4 v = rv[k];
      r[k * 4 + 0] = v.x; r[k * 4 + 1] = v.y;
      r[k * 4 + 2] = v.z; r[k * 4 + 3] = v.w;
    }
  }

  if (tid < BATCH * NCLS) lcnt[tid] = 0;
  __syncthreads();

  if (live) {
#pragma unroll
    for (int c = 0; c < NCLS; ++c) {
      if (r[c] > TSEL) atomicAdd(&lcnt[b * NCLS + c], 1);
    }
  }
  __syncthreads();

  if (tid < BATCH * NCLS) {
    int v = lcnt[tid];
    if (v > 0) lbase[tid] = atomicAdd(cnt + tid, v);
    lcnt[tid] = 0;                              // reuse as phase-C cursor
  }
  __syncthreads();

  if (live) {
#pragma unroll
    for (int c = 0; c < NCLS; ++c) {
      float s = r[c];
      if (s > TSEL) {
        int bc = b * NCLS + c;
        int p = atomicAdd(&lcnt[bc], 1);
        int pos = lbase[bc] + p;
        if (pos < CAP) {
          cand_s[(size_t)bc * CAP + pos] = s;
          cand_i[(size_t)bc * CAP + pos] = n;
        }
      }
    }
  }
}

// K2a: per-(b,c) bitonic sort of candidates; writes sorted keys + gathered
// sorted boxes to ws. (Phase-isolated for profiling.)
__global__ __launch_bounds__(NMS_T) void sort_kernel(
    const float* __restrict__ cand_s, const int* __restrict__ cand_i,
    const int* __restrict__ cnt, const float* __restrict__ boxes,
    u64* __restrict__ skeys, float4* __restrict__ sbox) {
  __shared__ u64 keys[CAP];                    // 8 KB
  const int bc  = blockIdx.x;
  const int tid = threadIdx.x;
  const int count = cnt[bc];
  if (count > CAP) return;                     // overflow -> walk_kernel full-N
  const int b = bc / NCLS;
  const float4* bxs = (const float4*)boxes + (size_t)b * N_ANCH;
  const float* cs = cand_s + (size_t)bc * CAP;
  const int*   ci = cand_i + (size_t)bc * CAP;
  // keys: (score_bits|msb)<<32 | ~idx — descending == greedy argmax order
  for (int g = tid; g < CAP; g += NMS_T) {
    u64 k = 0ull;                              // padding sinks to end
    if (g < count) {
      unsigned int u = __float_as_uint(cs[g]) | 0x80000000u;  // scores > 0
      k = ((u64)u << 32) | (unsigned int)(~ci[g]);
    }
    keys[g] = k;
  }
  __syncthreads();
  for (int kk = 2; kk <= CAP; kk <<= 1) {      // bitonic, descending
    for (int j = kk >> 1; j > 0; j >>= 1) {
#pragma unroll
      for (int p = 0; p < CAP / NMS_T; ++p) {
        int i = tid + p * NMS_T;
        int ixj = i ^ j;
        if (ixj > i) {
          u64 a = keys[i], bk = keys[ixj];
          bool ddir = ((i & kk) == 0);
          if ((a < bk) == ddir) { keys[i] = bk; keys[ixj] = a; }
        }
      }
      __syncthreads();
    }
  }
  u64*    sk = skeys + (size_t)bc * CAP;
  float4* sb = sbox  + (size_t)bc * CAP;
  for (int g = tid; g < count; g += NMS_T) {
    u64 k = keys[g];
    sk[g] = k;
    sb[g] = bxs[(int)(~((unsigned int)k))];    // gather -> coalesced write
  }
}

// K2b: build the 512x512 IoU bit-matrix, 8 row-strips/class in parallel
// (320 blocks). Word-major global layout [bc][w][r] -> lane-coalesced stores.
// Sub-diagonal / beyond-KM words stay garbage — harmless: the walk's cursor
// is monotone, so every bit j < pos is already decided when pos is accepted,
// and bits >= KM are pre-masked in the walk init.
__global__ __launch_bounds__(256) void build_kernel(
    const int* __restrict__ cnt, const float4* __restrict__ sbox,
    u64* __restrict__ matg) {
#pragma clang fp contract(off)
  __shared__ float4 cbox[KMAT];                // cols [r0, KM), 8 KB
  const int blk = blockIdx.x;
  const int bc  = blk >> 3;
  const int k   = blk & 7;
  const int count = cnt[bc];
  if (count > CAP) return;
  const int KM = (count < KMAT) ? count : KMAT;
  const int r0 = k * 64;
  if (r0 >= KM) return;
  const int tid = threadIdx.x;
  const float4* sb = sbox + (size_t)bc * CAP;
  const int ncols = KM - r0;
  for (int j = tid; j < ncols; j += 256) cbox[j] = sb[r0 + j];
  __syncthreads();
  const int lane = tid & 63;
  const int g    = tid >> 6;                   // 0..3
  const int r    = r0 + lane;                  // this lane's row
  if (r >= KM) return;
  const float4 rb = cbox[lane];
  const float  ra = (rb.z - rb.x) * (rb.w - rb.y);
  u64* mrow = matg + (size_t)bc * (KMAT * MATW);
  for (int w = k + g; w < MATW; w += 4) {      // w uniform per wave
    const int jb = w * 64;
    if (jb >= KM) break;
    const int jmax = (KM - jb < 64) ? (KM - jb) : 64;
    const int cb = jb - r0;                    // >= 0 since w >= k
    u64 bits = 0;
    for (int jj = 0; jj < jmax; ++jj) {
      float4 e = cbox[cb + jj];                // broadcast (uniform address)
      float ea = (e.z - e.x) * (e.w - e.y);
      bits |= (u64)iou_gt_fast(rb.x, rb.y, rb.z, rb.w, ra, e, ea) << jj;
    }
    mrow[(size_t)w * KMAT + r] = bits;         // coalesced across lanes
  }
}

// K2c: prefetch matrix -> LDS, single-lane monotone bit-walk, parallel tail
// (safety, dead on this input), emit. Exact full-N fallback on overflow or
// <300 total survivors.
__global__ __launch_bounds__(NMS_T) void walk_kernel(
    const float* __restrict__ cls, const float* __restrict__ boxes,
    const int* __restrict__ cnt, const u64* __restrict__ matg,
    const u64* __restrict__ skeys, const float4* __restrict__ sbox,
    float* __restrict__ sel_s, int* __restrict__ sel_i) {
#pragma clang fp contract(off)
  __shared__ u64    lmat[KMAT * MATW];         // 32 KB, [w][r]; reused as accb
  __shared__ float4 bxl[CAP + CAP / 16];       // 17 KB (padded: BXL)
  __shared__ int    apos[MAXDET];
  __shared__ u64    tailmask[8];
  __shared__ int    A_sh;
  __shared__ float  red_s[NMS_T / 64];
  __shared__ int    red_n[NMS_T / 64];
  __shared__ float  g_s;
  __shared__ int    g_n;

  const int bc  = blockIdx.x;
  const int b   = bc / NCLS;
  const int c   = bc - b * NCLS;
  const int tid = threadIdx.x;
  const int count = cnt[bc];
  float* ss = sel_s + (size_t)bc * MAXDET;
  int*   si = sel_i + (size_t)bc * MAXDET;
  const float4* bxs = (const float4*)boxes + (size_t)b * N_ANCH;
  bool fullfb = (count > CAP);

  if (!fullfb) {
    // block-parallel prefetch: matrix + sorted boxes -> LDS
    const u64* mg = matg + (size_t)bc * (KMAT * MATW);
    for (int j = tid; j < KMAT * MATW; j += NMS_T) lmat[j] = mg[j];
    const float4* sb = sbox + (size_t)bc * CAP;
    for (int g = tid; g < count; g += NMS_T) bxl[BXL(g)] = sb[g];
    __syncthreads();
    const int KM = (count < KMAT) ? count : KMAT;
    // single-lane monotone-cursor bit-walk over the greedy prefix
    if (tid == 0) {
      u64 m[MATW];
#pragma unroll
      for (int w = 0; w < MATW; ++w) {
        int base = w * 64;
        m[w] = (base >= KM) ? ~0ull
             : ((KM - base >= 64) ? 0ull : (~0ull << (KM - base)));
      }
      int A = 0, w0 = 0;
      while (true) {
        while (w0 < MATW && m[w0] == ~0ull) ++w0;
        if (w0 == MATW) break;
        const int pos = (w0 << 6) + __builtin_ctzll(~m[w0]);
        apos[A] = pos;
        A++;
        if (A == MAXDET) break;
        m[w0] |= 1ull << (pos & 63);           // self bit
#pragma unroll
        for (int w = 0; w < MATW; ++w) m[w] |= lmat[w * KMAT + pos];
      }
      A_sh = A;
    }
    __syncthreads();
    const int A0 = A_sh;

    // ---- parallel tail (safety; dead when A0 == 300)
    if (A0 < MAXDET && count > KMAT) {
      float4* accb = (float4*)lmat;            // lmat no longer needed
      float*  acca = (float*)(accb + MAXDET);
      if (tid < A0) {
        float4 v = bxl[BXL(apos[tid])];
        accb[tid] = v;
        acca[tid] = (v.z - v.x) * (v.w - v.y);
      }
      __syncthreads();
      {
        const int g = KMAT + tid;
        bool alive = (g < count);
        float4 bx = {0.0f, 0.0f, 0.0f, 0.0f};
        float carea = 0.0f;
        if (alive) {
          bx = bxl[BXL(g)];
          carea = (bx.z - bx.x) * (bx.w - bx.y);
        }
        for (int a = 0; a < A0; ++a) {
          if (!alive) break;
          float4 abx = accb[a];
          float  aar = acca[a];
          if (iou_gt_fast(abx.x, abx.y, abx.z, abx.w, aar, bx, carea))
            alive = false;
        }
        u64 bal = __ballot(alive);
        if ((tid & 63) == 0) tailmask[tid >> 6] = bal;
      }
      __syncthreads();
      if (tid < 64) {
        const int lane = tid;
        int A = A0;
        bool done = false;
        for (int w = 0; w < 8 && !done; ++w) {
          u64 mask = tailmask[w];
          if (!mask) continue;
          const int g = KMAT + (w << 6) + lane;
          const bool mine0 = (mask >> lane) & 1;
          float4 bx = {0.0f, 0.0f, 0.0f, 0.0f};
          float carea = 0.0f;
          if (mine0) {
            bx = bxl[BXL(g)];
            carea = (bx.z - bx.x) * (bx.w - bx.y);
          }
          bool alive = mine0;
          for (int a = A0; a < A; ++a) {
            if (!alive) break;
            float4 abx = accb[a];
            float  aar = acca[a];
            if (iou_gt_fast(abx.x, abx.y, abx.z, abx.w, aar, bx, carea))
              alive = false;
          }
          u64 pend = __ballot(alive);
          while (pend) {
            const int jj = __ffsll((long long)pend) - 1;
            pend &= pend - 1;
            const float jx = __shfl(bx.x, jj);
            const float jy = __shfl(bx.y, jj);
            const float jz = __shfl(bx.z, jj);
            const float jw = __shfl(bx.w, jj);
            if (lane == jj) {
              apos[A] = g;
              accb[A] = bx; acca[A] = carea;
            }
            A++;
            if (A == MAXDET) { done = true; break; }
            if (pend) {
              const float jar = (jz - jx) * (jw - jy);
              bool mine = (pend >> lane) & 1;
              bool sup = mine && iou_gt_fast(jx, jy, jz, jw, jar, bx, carea);
              pend &= ~__ballot(sup);
            }
          }
        }
        if (lane == 0) A_sh = A;
      }
      __syncthreads();
    }

    if (A_sh >= MAXDET) {
      if (tid < MAXDET) {                      // parallel emit (keys from L2)
        u64 key = skeys[(size_t)bc * CAP + apos[tid]];
        ss[tid] = __uint_as_float(((unsigned int)(key >> 32)) & 0x7FFFFFFFu);
        si[tid] = (int)(~((unsigned int)key));
      }
      return;
    }
    fullfb = true;
  }

  // ---- exact full-N fallback (correctness insurance)
  {
    const float* crow = cls + ((size_t)b * N_ANCH) * NCLS + c;  // stride NCLS
    const int base = tid * FB_PER;
    float sc[FB_PER];
#pragma unroll
    for (int m = 0; m < FB_PER; ++m) {
      int n = base + m;
      float v = DEAD;
      if (n < N_ANCH) {
        float r = crow[(size_t)n * NCLS];
        v = (r > SCTHR) ? r : NEGF;
      }
      sc[m] = v;
    }
    __syncthreads();
    for (int k = 0; k < MAXDET; ++k) {
      float bs = DEAD; int bn = 0x7FFFFFFF;
#pragma unroll
      for (int m = 0; m < FB_PER; ++m) {
        if (sc[m] > bs) { bs = sc[m]; bn = base + m; }
      }
      block_argmax(bs, bn, red_s, red_n, &g_s, &g_n);
      const float gs = g_s; const int gn = g_n;
      if (tid == 0) { ss[k] = gs; si[k] = gn; }
      float4 w4 = bxs[gn];
      float ab = (w4.z - w4.x) * (w4.w - w4.y);
#pragma unroll
      for (int m = 0; m < FB_PER; ++m) {
        if (sc[m] > NEGF) {
          float4 e = bxs[base + m];
          if (iou_gt(w4.x, w4.y, w4.z, w4.w, ab, e)) sc[m] = NEGF;
        }
      }
    }
  }
}

// K3: stable global top-300 per batch. Pivot prune + exact rank-count.
__global__ __launch_bounds__(512) void topk_kernel(
    const float* __restrict__ sel_s, const int* __restrict__ sel_i,
    const float* __restrict__ boxes, float* __restrict__ out) {
#pragma clang fp contract(off)
  __shared__ u64 keys[NCLS * MAXDET];   // 48 KB
  __shared__ int ccnt[NCLS];
  __shared__ u64 Psh;
  const int b = blockIdx.x;
  const int tid = threadIdx.x;
  const float* ssb = sel_s + (size_t)b * NCLS * MAXDET;
  const int*   sib = sel_i + (size_t)b * NCLS * MAXDET;
  for (int e = tid; e < NCLS * MAXDET; e += 512) {
    unsigned int u = __float_as_uint(ssb[e]);
    u = (u & 0x80000000u) ? ~u : (u | 0x80000000u);    // order-preserving map
    keys[e] = ((u64)u << 32) | (u64)(0xFFFFFFFFu - (unsigned)e);
  }
  __syncthreads();
  if (tid == 0) {
    u64 mn = ~0ull;
    for (int c = 0; c < NCLS; ++c) {
      u64 v = keys[c * MAXDET + 29];
      if (v < mn) mn = v;
    }
    Psh = mn;
  }
  __syncthreads();
  const u64 P = Psh;
  if (tid < NCLS) {
    const u64* kc = keys + tid * MAXDET;
    int lo = 0, hi = MAXDET;
    while (lo < hi) { int mid = (lo + hi) >> 1; if (kc[mid] >= P) lo = mid + 1; else hi = mid; }
    ccnt[tid] = lo;
  }
  __syncthreads();
  for (int e = tid; e < NCLS * MAXDET; e += 512) {
    int c = e / MAXDET;
    int j = e - c * MAXDET;
    if (j >= ccnt[c]) continue;
    u64 ke = keys[e];
    int rank = 0;
    for (int c2 = 0; c2 < NCLS; ++c2) {
      const u64* kc = keys + c2 * MAXDET;
      int lo = 0, hi = ccnt[c2];
      while (lo < hi) {
        int mid = (lo + hi) >> 1;
        if (kc[mid] > ke) lo = mid + 1; else hi = mid;
      }
      rank += lo;
    }
    if (rank < MAXDET) {
      float s = ssb[e];
      int   n = sib[e];
      bool valid = (s > NEGF * 0.5f);
      float4 bx = ((const float4*)boxes)[(size_t)b * N_ANCH + n];
      float* ob = out + ((size_t)b * MAXDET + rank) * 4;
      ob[0] = valid ? bx.x : -1.0f;
      ob[1] = valid ? bx.y : -1.0f;
      ob[2] = valid ? bx.z : -1.0f;
      ob[3] = valid ? bx.w : -1.0f;
      out[(size_t)BATCH * MAXDET * 4 + (size_t)b * MAXDET + rank] = valid ? s : -1.0f;
      out[(size_t)BATCH * MAXDET * 5 + (size_t)b * MAXDET + rank] =
          valid ? (float)c : -1.0f;
    }
  }
}

extern "C" void kernel_launch(void* const* d_in, const int* in_sizes, int n_in,
                              void* d_out, int out_size, void* d_ws, size_t ws_size,
                              hipStream_t stream) {
  (void)in_sizes; (void)n_in; (void)out_size; (void)ws_size;
  const float* anchors = (const float*)d_in[1];
  const float* deltas  = (const float*)d_in[2];
  const float* cls     = (const float*)d_in[3];   // d_in[0] = image: only shape used
  char* ws = (char*)d_ws;
  float*  boxes  = (float*) (ws + OFF_BOXES);
  float*  cand_s = (float*) (ws + OFF_CS);
  int*    cand_i = (int*)   (ws + OFF_CI);
  int*    cnt    = (int*)   (ws + OFF_CNT);
  float*  sel_s  = (float*) (ws + OFF_SS);
  int*    sel_i  = (int*)   (ws + OFF_SI);
  u64*    skeys  = (u64*)   (ws + OFF_SK);
  float4* sbox   = (float4*)(ws + OFF_SB);
  u64*    matg   = (u64*)   (ws + OFF_MAT);

  hipMemsetAsync(cnt, 0, SZ_CNT, stream);   // ws is re-poisoned 0xAA each call

  dec_gather<<<(BATCH * N_ANCH + 255) / 256, 256, 0, stream>>>(
      anchors, deltas, cls, boxes, cand_s, cand_i, cnt);
  sort_kernel<<<BATCH * NCLS, NMS_T, 0, stream>>>(
      cand_s, cand_i, cnt, boxes, skeys, sbox);
  build_kernel<<<BATCH * NCLS * 8, 256, 0, stream>>>(cnt, sbox, matg);
  walk_kernel<<<BATCH * NCLS, NMS_T, 0, stream>>>(
      cls, boxes, cnt, matg, skeys, sbox, sel_s, sel_i);
  topk_kernel<<<BATCH, 512, 0, stream>>>(sel_s, sel_i, boxes, (float*)d_out);
}